// Round 8
// baseline (173.120 us; speedup 1.0000x reference)
//
#include <hip/hip_runtime.h>
#include <stdint.h>

#define T_SEQ 2048
#define CIN 256
#define COUT 512
#define NHEAD 8
#define DH 64

typedef __bf16 bf16x8 __attribute__((ext_vector_type(8)));
typedef float f32x4 __attribute__((ext_vector_type(4)));
typedef float f32x16 __attribute__((ext_vector_type(16)));
typedef unsigned short u16x8 __attribute__((ext_vector_type(8)));
typedef unsigned u32x4 __attribute__((ext_vector_type(4)));

static __device__ __forceinline__ unsigned short bf16_rne(float f) {
  unsigned u = __builtin_bit_cast(unsigned, f);
  u += 0x7FFFu + ((u >> 16) & 1u);
  return (unsigned short)(u >> 16);
}

static __device__ __forceinline__ unsigned cvt_pk_bf16(float lo, float hi) {
  unsigned r;
  asm("v_cvt_pk_bf16_f32 %0, %1, %2" : "=v"(r) : "v"(lo), "v"(hi));
  return r;
}

// in-place cross-half swap (T12)
static __device__ __forceinline__ void plswap(unsigned& a, unsigned& b) {
  auto rr = __builtin_amdgcn_permlane32_swap((int)a, (int)b, false, false);
  a = (unsigned)rr[0];
  b = (unsigned)rr[1];
}

static __device__ __forceinline__ bf16x8 ld_frag(const unsigned short* p) {
  u16x8 v = *(const u16x8*)p;
  return __builtin_bit_cast(bf16x8, v);
}

// ---------------- pack: weights f32 -> bf16 ----------------
__global__ __launch_bounds__(256) void pack_w_k(const float* __restrict__ wq,
                                                const float* __restrict__ wk,
                                                const float* __restrict__ wv,
                                                unsigned short* __restrict__ wb) {
  int i = blockIdx.x * 256 + threadIdx.x;
  const float* src = (i < 131072) ? wq : (i < 262144) ? wk : wv;
  wb[i] = bf16_rne(src[i & 131071]);
}

// ---------------- pack: x (n,c,t) f32 -> xT (n,t,c) bf16 ----------------
__global__ __launch_bounds__(256) void pack_xT_k(const float* __restrict__ x,
                                                 unsigned short* __restrict__ xT) {
  __shared__ float tile[64][65];
  const int n = blockIdx.z, c0 = blockIdx.y * 64, t0 = blockIdx.x * 64;
  const int i = threadIdx.x;
  {
    const int cc = i >> 2, tch = (i & 3) * 16;
    const float* src = x + ((size_t)n * CIN + c0 + cc) * T_SEQ + t0 + tch;
    const float4* s4 = (const float4*)src;
#pragma unroll
    for (int q = 0; q < 4; ++q) {
      float4 v = s4[q];
      tile[cc][tch + q * 4 + 0] = v.x;
      tile[cc][tch + q * 4 + 1] = v.y;
      tile[cc][tch + q * 4 + 2] = v.z;
      tile[cc][tch + q * 4 + 3] = v.w;
    }
  }
  __syncthreads();
  {
    const int tt = i >> 2, cch = (i & 3) * 16;
    unsigned short* dst = xT + ((size_t)n * T_SEQ + t0 + tt) * CIN + c0 + cch;
    u16x8 w0, w1;
#pragma unroll
    for (int j = 0; j < 8; ++j) w0[j] = bf16_rne(tile[cch + j][tt]);
#pragma unroll
    for (int j = 0; j < 8; ++j) w1[j] = bf16_rne(tile[cch + 8 + j][tt]);
    *(u16x8*)dst = w0;
    *(u16x8*)(dst + 8) = w1;
  }
}

// ---------------- projection (V written d-major via LDS transpose) ----------------
__global__ __launch_bounds__(256) void proj_k(const unsigned short* __restrict__ wb,
                                              const unsigned short* __restrict__ xT,
                                              unsigned short* __restrict__ qb,
                                              unsigned short* __restrict__ kb,
                                              unsigned short* __restrict__ vb) {
  __shared__ unsigned short vt_lds[64][136];  // 64 o x 128 t, stride 136 (16B-aligned rows)
  const int z = blockIdx.z;
  const int n = z / 3, w = z % 3;
  const unsigned short* W = wb + (size_t)w * COUT * CIN;
  const unsigned short* X = xT + (size_t)n * T_SEQ * CIN;
  const int tid = threadIdx.x, wave = tid >> 6, lane = tid & 63;
  const int c = lane & 15, g = lane >> 4;
  const int o0 = blockIdx.x * 64;
  const int t0 = blockIdx.y * 128 + wave * 32;

  f32x4 acc[2][4];
  const f32x4 z4 = {0.f, 0.f, 0.f, 0.f};
#pragma unroll
  for (int mt = 0; mt < 2; ++mt)
#pragma unroll
    for (int no = 0; no < 4; ++no) acc[mt][no] = z4;

  for (int c0 = 0; c0 < CIN; c0 += 32) {
    bf16x8 a[2], b[4];
#pragma unroll
    for (int mt = 0; mt < 2; ++mt)
      a[mt] = ld_frag(X + (size_t)(t0 + mt * 16 + c) * CIN + c0 + g * 8);
#pragma unroll
    for (int no = 0; no < 4; ++no)
      b[no] = ld_frag(W + (size_t)(o0 + no * 16 + c) * CIN + c0 + g * 8);
#pragma unroll
    for (int mt = 0; mt < 2; ++mt)
#pragma unroll
      for (int no = 0; no < 4; ++no)
        acc[mt][no] = __builtin_amdgcn_mfma_f32_16x16x32_bf16(a[mt], b[no], acc[mt][no], 0, 0, 0);
  }

  const int h = o0 >> 6;
  const size_t base = ((size_t)(n * NHEAD + h)) * T_SEQ * DH;
  if (w == 2) {
    // stage to LDS d-major, then coalesced global store
#pragma unroll
    for (int mt = 0; mt < 2; ++mt)
#pragma unroll
      for (int no = 0; no < 4; ++no) {
        const int d = no * 16 + c;
        const int lt = (wave * 32) + mt * 16 + 4 * g;
#pragma unroll
        for (int pr = 0; pr < 2; ++pr) {
          const unsigned pw = (unsigned)bf16_rne(acc[mt][no][2 * pr]) |
                              ((unsigned)bf16_rne(acc[mt][no][2 * pr + 1]) << 16);
          *(unsigned*)&vt_lds[d][lt + 2 * pr] = pw;
        }
      }
    __syncthreads();
    const int row = tid >> 2, seg = tid & 3;
    unsigned short* dst = vb + base + (size_t)row * T_SEQ + blockIdx.y * 128 + seg * 32;
    const unsigned short* srcl = &vt_lds[row][seg * 32];
#pragma unroll
    for (int q = 0; q < 4; ++q) *(u16x8*)(dst + q * 8) = *(const u16x8*)(srcl + q * 8);
  } else {
    unsigned short* dst = (w == 0) ? qb : kb;
    // fold 1/sqrt(dk) * log2(e) into q so attention uses exp2 directly
    const float scale = (w == 0) ? 0.18033688011112043f : 1.0f;
#pragma unroll
    for (int mt = 0; mt < 2; ++mt)
#pragma unroll
      for (int no = 0; no < 4; ++no)
#pragma unroll
        for (int r = 0; r < 4; ++r) {
          const int t = t0 + mt * 16 + 4 * g + r;
          const int d = no * 16 + c;
          dst[base + (size_t)t * DH + d] = bf16_rne(acc[mt][no][r] * scale);
        }
  }
}

// ---------------- flash attention: no LDS, no barriers; frags direct from L1/L2 ----------------
// grid 512 (XCD-swizzled -> 16 tq-tiles x 32 nh), block 256 (4 waves x 32 tq). KV tile 64.
// 32x32x16 MFMA; in-register softmax via cvt_pk + permlane32_swap; no max tracking.
__global__ __launch_bounds__(256) void attn_k(const unsigned short* __restrict__ qb,
                                              const unsigned short* __restrict__ kb,
                                              const unsigned short* __restrict__ vbt,
                                              float* __restrict__ outp) {
  // XCD-bijective swizzle: 512 blocks, 8 XCDs -> 64 contiguous sids per XCD (4 nh panels)
  const int bid = blockIdx.x;
  const int sid = (bid & 7) * 64 + (bid >> 3);
  const int tqt = sid & 15, nh = sid >> 4;

  const int tid = threadIdx.x;
  const int wave = tid >> 6, lane = tid & 63;
  const int ln = lane & 31, hi = lane >> 5;
  const int tq0 = tqt * 128 + wave * 32;
  const unsigned short* Q = qb + (size_t)nh * T_SEQ * DH;
  const unsigned short* K = kb + (size_t)nh * T_SEQ * DH;   // [t][d]
  const unsigned short* V = vbt + (size_t)nh * T_SEQ * DH;  // [d][t]

  // Q fragments: B-operand, lane ln = tq col, k = d = dblk*16 + hi*8 + j
  bf16x8 qf[4];
#pragma unroll
  for (int dblk = 0; dblk < 4; ++dblk)
    qf[dblk] = ld_frag(Q + (size_t)(tq0 + ln) * DH + dblk * 16 + hi * 8);

  const f32x16 z16 = {0.f, 0.f, 0.f, 0.f, 0.f, 0.f, 0.f, 0.f,
                      0.f, 0.f, 0.f, 0.f, 0.f, 0.f, 0.f, 0.f};
  f32x16 oacc0 = z16, oacc1 = z16;  // O cols: oacc0 -> d=ln, oacc1 -> d=32+ln
  float l_run = 0.f;

  // per-lane fragment base pointers
  const unsigned short* kfb = K + (size_t)ln * DH + hi * 8;     // + t*64*DH (+32*DH for ka1) + dblk*16
  const unsigned short* vfb = V + (size_t)ln * T_SEQ + hi * 8;  // + t*64 (+32*T_SEQ for vf1) + kbk*16

  const int NT = T_SEQ / 64;
  for (int t = 0; t < NT; ++t) {
    const unsigned short* kt = kfb + (size_t)t * (64 * DH);
    const unsigned short* vt = vfb + (size_t)t * 64;
    // issue all fragment loads (L1/L2-resident; shared across waves/blocks of same nh)
    bf16x8 ka0[4], ka1[4], vf0[4], vf1[4];
#pragma unroll
    for (int dblk = 0; dblk < 4; ++dblk) {
      ka0[dblk] = ld_frag(kt + dblk * 16);
      ka1[dblk] = ld_frag(kt + 32 * DH + dblk * 16);
    }
#pragma unroll
    for (int kbk = 0; kbk < 4; ++kbk) {
      vf0[kbk] = ld_frag(vt + kbk * 16);
      vf1[kbk] = ld_frag(vt + 32 * T_SEQ + kbk * 16);
    }
    // ---- S = K x Q (A = K rows tk, B = Q cols tq), two tk-halves ----
    f32x16 sa0 = z16, sa1 = z16;
    __builtin_amdgcn_s_setprio(1);
#pragma unroll
    for (int dblk = 0; dblk < 4; ++dblk) {
      sa0 = __builtin_amdgcn_mfma_f32_32x32x16_bf16(ka0[dblk], qf[dblk], sa0, 0, 0, 0);
      sa1 = __builtin_amdgcn_mfma_f32_32x32x16_bf16(ka1[dblk], qf[dblk], sa1, 0, 0, 0);
    }
    __builtin_amdgcn_s_setprio(0);
    // ---- softmax numerator in-register: p = exp2(s); colsum; pack ----
    float p0[16], p1[16];
    float cs = 0.f;
#pragma unroll
    for (int r = 0; r < 16; ++r) {
      p0[r] = __builtin_amdgcn_exp2f(sa0[r]);
      p1[r] = __builtin_amdgcn_exp2f(sa1[r]);
      cs += p0[r] + p1[r];
    }
    cs += __shfl_xor(cs, 32);
    l_run += cs;
    unsigned W0[8], W1[8];
#pragma unroll
    for (int j = 0; j < 8; ++j) {
      W0[j] = cvt_pk_bf16(p0[2 * j], p0[2 * j + 1]);
      W1[j] = cvt_pk_bf16(p1[2 * j], p1[2 * j + 1]);
    }
    // ---- redistribute to PV A-fragments via permlane32_swap (T12) ----
    plswap(W0[0], W0[2]);
    plswap(W0[1], W0[3]);
    plswap(W0[4], W0[6]);
    plswap(W0[5], W0[7]);
    plswap(W1[0], W1[2]);
    plswap(W1[1], W1[3]);
    plswap(W1[4], W1[6]);
    plswap(W1[5], W1[7]);
    bf16x8 pa[4];
    {
      u32x4 f;
      f[0] = W0[0]; f[1] = W0[1]; f[2] = W0[2]; f[3] = W0[3];
      pa[0] = __builtin_bit_cast(bf16x8, f);
      f[0] = W0[4]; f[1] = W0[5]; f[2] = W0[6]; f[3] = W0[7];
      pa[1] = __builtin_bit_cast(bf16x8, f);
      f[0] = W1[0]; f[1] = W1[1]; f[2] = W1[2]; f[3] = W1[3];
      pa[2] = __builtin_bit_cast(bf16x8, f);
      f[0] = W1[4]; f[1] = W1[5]; f[2] = W1[6]; f[3] = W1[7];
      pa[3] = __builtin_bit_cast(bf16x8, f);
    }
    // ---- PV: O[tq][d] += P x V ----
    __builtin_amdgcn_s_setprio(1);
#pragma unroll
    for (int kbk = 0; kbk < 4; ++kbk) {
      oacc0 = __builtin_amdgcn_mfma_f32_32x32x16_bf16(pa[kbk], vf0[kbk], oacc0, 0, 0, 0);
      oacc1 = __builtin_amdgcn_mfma_f32_32x32x16_bf16(pa[kbk], vf1[kbk], oacc1, 0, 0, 0);
    }
    __builtin_amdgcn_s_setprio(0);
  }

  // ---- epilogue: l redistribution via shuffles (no LDS), normalize, store ----
  const int n = nh >> 3, h = nh & 7;
  const size_t obase = (size_t)(n * COUT + h * DH) * T_SEQ;
  const int d0 = ln, d1 = 32 + ln;
#pragma unroll
  for (int rq = 0; rq < 4; ++rq) {
    const int tbase = tq0 + 8 * rq + 4 * hi;
    f32x4 o0, o1;
#pragma unroll
    for (int j = 0; j < 4; ++j) {
      const float lv = __shfl(l_run, 8 * rq + 4 * hi + j);
      const float inv = __builtin_amdgcn_rcpf(lv);
      o0[j] = oacc0[4 * rq + j] * inv;
      o1[j] = oacc1[4 * rq + j] * inv;
    }
    *(f32x4*)&outp[obase + (size_t)d0 * T_SEQ + tbase] = o0;
    *(f32x4*)&outp[obase + (size_t)d1 * T_SEQ + tbase] = o1;
  }
}

extern "C" void kernel_launch(void* const* d_in, const int* in_sizes, int n_in,
                              void* d_out, int out_size, void* d_ws, size_t ws_size,
                              hipStream_t stream) {
  (void)in_sizes; (void)n_in; (void)out_size; (void)ws_size;
  const float* x  = (const float*)d_in[0];
  const float* Wq = (const float*)d_in[1];
  const float* Wk = (const float*)d_in[2];
  const float* Wv = (const float*)d_in[3];
  float* outp = (float*)d_out;

  char* ws = (char*)d_ws;
  unsigned short* wb = (unsigned short*)ws;                       // 786432 B
  unsigned short* xT = (unsigned short*)(ws + 786432);            // 4194304 B
  unsigned short* qb = (unsigned short*)(ws + 4980736);           // 8388608 B each
  unsigned short* kb = qb + 4194304;
  unsigned short* vb = kb + 4194304;                              // vb is d-major [nh][64][2048]

  pack_w_k<<<1536, 256, 0, stream>>>(Wq, Wk, Wv, wb);
  pack_xT_k<<<dim3(32, 4, 4), 256, 0, stream>>>(x, xT);
  proj_k<<<dim3(8, 16, 12), 256, 0, stream>>>(wb, xT, qb, kb, vb);
  attn_k<<<512, 256, 0, stream>>>(qb, kb, vb, outp);
}

// Round 9
// 105.522 us; speedup vs baseline: 1.6406x; 1.6406x over previous
//
#include <hip/hip_runtime.h>
#include <stdint.h>

#define T_SEQ 2048
#define CIN 256
#define COUT 512
#define NHEAD 8
#define DH 64
#define LROW 72  // LDS row stride in elems (144B: 16B-aligned, 9 granules -> even bank spread)

typedef __bf16 bf16x8 __attribute__((ext_vector_type(8)));
typedef float f32x4 __attribute__((ext_vector_type(4)));
typedef float f32x16 __attribute__((ext_vector_type(16)));
typedef unsigned short u16x8 __attribute__((ext_vector_type(8)));
typedef unsigned u32x4 __attribute__((ext_vector_type(4)));

static __device__ __forceinline__ unsigned short bf16_rne(float f) {
  unsigned u = __builtin_bit_cast(unsigned, f);
  u += 0x7FFFu + ((u >> 16) & 1u);
  return (unsigned short)(u >> 16);
}

static __device__ __forceinline__ unsigned cvt_pk_bf16(float lo, float hi) {
  unsigned r;
  asm("v_cvt_pk_bf16_f32 %0, %1, %2" : "=v"(r) : "v"(lo), "v"(hi));
  return r;
}

// in-place cross-half swap (T12)
static __device__ __forceinline__ void plswap(unsigned& a, unsigned& b) {
  auto rr = __builtin_amdgcn_permlane32_swap((int)a, (int)b, false, false);
  a = (unsigned)rr[0];
  b = (unsigned)rr[1];
}

static __device__ __forceinline__ bf16x8 ld_frag(const unsigned short* p) {
  u16x8 v = *(const u16x8*)p;
  return __builtin_bit_cast(bf16x8, v);
}

// ---------------- pack: weights f32 -> bf16 ----------------
__global__ __launch_bounds__(256) void pack_w_k(const float* __restrict__ wq,
                                                const float* __restrict__ wk,
                                                const float* __restrict__ wv,
                                                unsigned short* __restrict__ wb) {
  int i = blockIdx.x * 256 + threadIdx.x;
  const float* src = (i < 131072) ? wq : (i < 262144) ? wk : wv;
  wb[i] = bf16_rne(src[i & 131071]);
}

// ---------------- pack: x (n,c,t) f32 -> xT (n,t,c) bf16 ----------------
__global__ __launch_bounds__(256) void pack_xT_k(const float* __restrict__ x,
                                                 unsigned short* __restrict__ xT) {
  __shared__ float tile[64][65];
  const int n = blockIdx.z, c0 = blockIdx.y * 64, t0 = blockIdx.x * 64;
  const int i = threadIdx.x;
  {
    const int cc = i >> 2, tch = (i & 3) * 16;
    const float* src = x + ((size_t)n * CIN + c0 + cc) * T_SEQ + t0 + tch;
    const float4* s4 = (const float4*)src;
#pragma unroll
    for (int q = 0; q < 4; ++q) {
      float4 v = s4[q];
      tile[cc][tch + q * 4 + 0] = v.x;
      tile[cc][tch + q * 4 + 1] = v.y;
      tile[cc][tch + q * 4 + 2] = v.z;
      tile[cc][tch + q * 4 + 3] = v.w;
    }
  }
  __syncthreads();
  {
    const int tt = i >> 2, cch = (i & 3) * 16;
    unsigned short* dst = xT + ((size_t)n * T_SEQ + t0 + tt) * CIN + c0 + cch;
    u16x8 w0, w1;
#pragma unroll
    for (int j = 0; j < 8; ++j) w0[j] = bf16_rne(tile[cch + j][tt]);
#pragma unroll
    for (int j = 0; j < 8; ++j) w1[j] = bf16_rne(tile[cch + 8 + j][tt]);
    *(u16x8*)dst = w0;
    *(u16x8*)(dst + 8) = w1;
  }
}

// ---------------- projection (V written d-major via LDS transpose) ----------------
__global__ __launch_bounds__(256) void proj_k(const unsigned short* __restrict__ wb,
                                              const unsigned short* __restrict__ xT,
                                              unsigned short* __restrict__ qb,
                                              unsigned short* __restrict__ kb,
                                              unsigned short* __restrict__ vb) {
  __shared__ unsigned short vt_lds[64][136];  // 64 o x 128 t, stride 136 (16B-aligned rows)
  const int z = blockIdx.z;
  const int n = z / 3, w = z % 3;
  const unsigned short* W = wb + (size_t)w * COUT * CIN;
  const unsigned short* X = xT + (size_t)n * T_SEQ * CIN;
  const int tid = threadIdx.x, wave = tid >> 6, lane = tid & 63;
  const int c = lane & 15, g = lane >> 4;
  const int o0 = blockIdx.x * 64;
  const int t0 = blockIdx.y * 128 + wave * 32;

  f32x4 acc[2][4];
  const f32x4 z4 = {0.f, 0.f, 0.f, 0.f};
#pragma unroll
  for (int mt = 0; mt < 2; ++mt)
#pragma unroll
    for (int no = 0; no < 4; ++no) acc[mt][no] = z4;

  for (int c0 = 0; c0 < CIN; c0 += 32) {
    bf16x8 a[2], b[4];
#pragma unroll
    for (int mt = 0; mt < 2; ++mt)
      a[mt] = ld_frag(X + (size_t)(t0 + mt * 16 + c) * CIN + c0 + g * 8);
#pragma unroll
    for (int no = 0; no < 4; ++no)
      b[no] = ld_frag(W + (size_t)(o0 + no * 16 + c) * CIN + c0 + g * 8);
#pragma unroll
    for (int mt = 0; mt < 2; ++mt)
#pragma unroll
      for (int no = 0; no < 4; ++no)
        acc[mt][no] = __builtin_amdgcn_mfma_f32_16x16x32_bf16(a[mt], b[no], acc[mt][no], 0, 0, 0);
  }

  const int h = o0 >> 6;
  const size_t base = ((size_t)(n * NHEAD + h)) * T_SEQ * DH;
  if (w == 2) {
    // stage to LDS d-major, then coalesced global store
#pragma unroll
    for (int mt = 0; mt < 2; ++mt)
#pragma unroll
      for (int no = 0; no < 4; ++no) {
        const int d = no * 16 + c;
        const int lt = (wave * 32) + mt * 16 + 4 * g;
#pragma unroll
        for (int pr = 0; pr < 2; ++pr) {
          const unsigned pw = (unsigned)bf16_rne(acc[mt][no][2 * pr]) |
                              ((unsigned)bf16_rne(acc[mt][no][2 * pr + 1]) << 16);
          *(unsigned*)&vt_lds[d][lt + 2 * pr] = pw;
        }
      }
    __syncthreads();
    const int row = tid >> 2, seg = tid & 3;
    unsigned short* dst = vb + base + (size_t)row * T_SEQ + blockIdx.y * 128 + seg * 32;
    const unsigned short* srcl = &vt_lds[row][seg * 32];
#pragma unroll
    for (int q = 0; q < 4; ++q) *(u16x8*)(dst + q * 8) = *(const u16x8*)(srcl + q * 8);
  } else {
    unsigned short* dst = (w == 0) ? qb : kb;
    // fold 1/sqrt(dk) * log2(e) into q so attention uses exp2 directly
    const float scale = (w == 0) ? 0.18033688011112043f : 1.0f;
#pragma unroll
    for (int mt = 0; mt < 2; ++mt)
#pragma unroll
      for (int no = 0; no < 4; ++no)
#pragma unroll
        for (int r = 0; r < 4; ++r) {
          const int t = t0 + mt * 16 + 4 * g + r;
          const int d = no * 16 + c;
          dst[base + (size_t)t * DH + d] = bf16_rne(acc[mt][no][r] * scale);
        }
  }
}

// ---------------- flash attention: 8 waves, in-block tk-split (2 halves), LDS dbuf ----------------
// grid 512 (XCD-swizzled -> 16 tq-tiles x 32 nh), block 512 (2 tk-halves x 4 waves x 32 tq).
// 32x32x16 MFMA; in-register softmax via cvt_pk + permlane32_swap; no max tracking (bounded scores);
// exact end-merge: O = O_a + O_b, l = l_a + l_b (plain sums, no rescale needed).
__global__ __launch_bounds__(512) void attn_k(const unsigned short* __restrict__ qb,
                                              const unsigned short* __restrict__ kb,
                                              const unsigned short* __restrict__ vbt,
                                              float* __restrict__ outp) {
  __shared__ unsigned short Kl[2][2][64 * LROW];  // [half][dbuf]; rows tk, d contiguous
  __shared__ unsigned short Vt[2][2][64 * LROW];  // [half][dbuf]; rows d, tk contiguous

  // XCD-bijective swizzle: 512 blocks, 8 XCDs -> 64 contiguous sids per XCD
  const int bid = blockIdx.x;
  const int sid = (bid & 7) * 64 + (bid >> 3);
  const int tqt = sid & 15, nh = sid >> 4;

  const int tid = threadIdx.x;
  const int wave = tid >> 6, lane = tid & 63;
  const int half = wave >> 2;           // tk half: 0 -> [0,1024), 1 -> [1024,2048)
  const int ln = lane & 31, hi = lane >> 5;
  const int tq0 = tqt * 128 + (wave & 3) * 32;
  const unsigned short* Q = qb + (size_t)nh * T_SEQ * DH;
  const unsigned short* K = kb + (size_t)nh * T_SEQ * DH;   // [t][d]
  const unsigned short* V = vbt + (size_t)nh * T_SEQ * DH;  // [d][t]

  // Q fragments: B-operand, lane ln = tq col, k = d = dblk*16 + hi*8 + j
  bf16x8 qf[4];
#pragma unroll
  for (int dblk = 0; dblk < 4; ++dblk)
    qf[dblk] = ld_frag(Q + (size_t)(tq0 + ln) * DH + dblk * 16 + hi * 8);

  const f32x16 z16 = {0.f, 0.f, 0.f, 0.f, 0.f, 0.f, 0.f, 0.f,
                      0.f, 0.f, 0.f, 0.f, 0.f, 0.f, 0.f, 0.f};
  f32x16 oacc0 = z16, oacc1 = z16;  // O cols: oacc0 -> d=ln, oacc1 -> d=32+ln
  float l_run = 0.f;

  // ---- staging decomposition within half (256 threads): row = ht&63, seg = ht>>6 ----
  const int ht = tid & 255;
  const int srow = ht & 63, sseg = ht >> 6;
  const unsigned short* kseg = K + (size_t)(half * 1024 + srow) * DH + sseg * 16;  // +64*DH/tile
  const unsigned short* vseg = V + (size_t)srow * T_SEQ + half * 1024 + sseg * 16; // +64/tile
  const int swoff = srow * LROW + sseg * 16;
  // read row offsets (elems)
  const int row0 = ln * LROW;
  const int row1 = (32 + ln) * LROW;
  const int hioff = hi * 8;

  // ---- prologue: stage tile 0 of this half ----
  unsigned short* krb = &Kl[half][0][0];
  unsigned short* kab = &Kl[half][1][0];
  unsigned short* vrb = &Vt[half][0][0];
  unsigned short* vab = &Vt[half][1][0];
  {
    u16x8 k0 = *(const u16x8*)kseg;
    u16x8 k1 = *(const u16x8*)(kseg + 8);
    u16x8 v0 = *(const u16x8*)vseg;
    u16x8 v1 = *(const u16x8*)(vseg + 8);
    *(u16x8*)&krb[swoff] = k0;
    *(u16x8*)&krb[swoff + 8] = k1;
    *(u16x8*)&vrb[swoff] = v0;
    *(u16x8*)&vrb[swoff + 8] = v1;
  }
  __syncthreads();

  const int NT2 = T_SEQ / 64 / 2;  // 16 tiles per half
  for (int t = 0; t < NT2; ++t) {
    const bool pre = (t + 1 < NT2);
    u16x8 kn0, kn1, vn0, vn1;
    if (pre) {  // issue next-tile global loads early (written to LDS after PV)
      const unsigned short* ks = kseg + (size_t)(t + 1) * (64 * DH);
      kn0 = *(const u16x8*)ks;
      kn1 = *(const u16x8*)(ks + 8);
      const unsigned short* vs = vseg + (size_t)(t + 1) * 64;
      vn0 = *(const u16x8*)vs;
      vn1 = *(const u16x8*)(vs + 8);
    }
    // ---- S = K x Q (A = K rows tk, B = Q cols tq), two tk-32-halves ----
    f32x16 sa0 = z16, sa1 = z16;
    __builtin_amdgcn_s_setprio(1);
#pragma unroll
    for (int dblk = 0; dblk < 4; ++dblk) {
      bf16x8 ka0 = ld_frag(krb + row0 + dblk * 16 + hioff);
      bf16x8 ka1 = ld_frag(krb + row1 + dblk * 16 + hioff);
      sa0 = __builtin_amdgcn_mfma_f32_32x32x16_bf16(ka0, qf[dblk], sa0, 0, 0, 0);
      sa1 = __builtin_amdgcn_mfma_f32_32x32x16_bf16(ka1, qf[dblk], sa1, 0, 0, 0);
    }
    __builtin_amdgcn_s_setprio(0);
    // ---- softmax numerator in-register: p = exp2(s); colsum; pack ----
    float p0[16], p1[16];
    float cs = 0.f;
#pragma unroll
    for (int r = 0; r < 16; ++r) {
      p0[r] = __builtin_amdgcn_exp2f(sa0[r]);
      p1[r] = __builtin_amdgcn_exp2f(sa1[r]);
      cs += p0[r] + p1[r];
    }
    cs += __shfl_xor(cs, 32);
    l_run += cs;
    unsigned W0[8], W1[8];
#pragma unroll
    for (int j = 0; j < 8; ++j) {
      W0[j] = cvt_pk_bf16(p0[2 * j], p0[2 * j + 1]);
      W1[j] = cvt_pk_bf16(p1[2 * j], p1[2 * j + 1]);
    }
    // ---- redistribute to PV A-fragments via permlane32_swap (T12) ----
    plswap(W0[0], W0[2]);
    plswap(W0[1], W0[3]);
    plswap(W0[4], W0[6]);
    plswap(W0[5], W0[7]);
    plswap(W1[0], W1[2]);
    plswap(W1[1], W1[3]);
    plswap(W1[4], W1[6]);
    plswap(W1[5], W1[7]);
    bf16x8 pa[4];
    {
      u32x4 f;
      f[0] = W0[0]; f[1] = W0[1]; f[2] = W0[2]; f[3] = W0[3];
      pa[0] = __builtin_bit_cast(bf16x8, f);
      f[0] = W0[4]; f[1] = W0[5]; f[2] = W0[6]; f[3] = W0[7];
      pa[1] = __builtin_bit_cast(bf16x8, f);
      f[0] = W1[0]; f[1] = W1[1]; f[2] = W1[2]; f[3] = W1[3];
      pa[2] = __builtin_bit_cast(bf16x8, f);
      f[0] = W1[4]; f[1] = W1[5]; f[2] = W1[6]; f[3] = W1[7];
      pa[3] = __builtin_bit_cast(bf16x8, f);
    }
    // ---- PV: O[tq][d] += P x V (A = P rows tq, B = V^T cols d from Vt rows) ----
    __builtin_amdgcn_s_setprio(1);
#pragma unroll
    for (int kbk = 0; kbk < 4; ++kbk) {
      bf16x8 vf0 = ld_frag(vrb + row0 + kbk * 16 + hioff);
      bf16x8 vf1 = ld_frag(vrb + row1 + kbk * 16 + hioff);
      oacc0 = __builtin_amdgcn_mfma_f32_32x32x16_bf16(pa[kbk], vf0, oacc0, 0, 0, 0);
      oacc1 = __builtin_amdgcn_mfma_f32_32x32x16_bf16(pa[kbk], vf1, oacc1, 0, 0, 0);
    }
    __builtin_amdgcn_s_setprio(0);
    // ---- write next K/V tiles into alt buffers ----
    if (pre) {
      *(u16x8*)&kab[swoff] = kn0;
      *(u16x8*)&kab[swoff + 8] = kn1;
      *(u16x8*)&vab[swoff] = vn0;
      *(u16x8*)&vab[swoff + 8] = vn1;
    }
    __syncthreads();
    unsigned short* tp;
    tp = krb; krb = kab; kab = tp;
    tp = vrb; vrb = vab; vab = tp;
  }

  // ---- merge halves: exact (no max tracking): O += O_partner, l += l_partner ----
  float* mbuf = (float*)&Kl[0][0][0];  // 4 waves x 2112 floats = 33.8KB (Kl = 36.9KB)
  const int MS = 2112;
  if (half == 1) {
    float* mb = mbuf + (wave - 4) * MS;
#pragma unroll
    for (int r = 0; r < 16; ++r) mb[r * 64 + lane] = oacc0[r];
#pragma unroll
    for (int r = 0; r < 16; ++r) mb[1024 + r * 64 + lane] = oacc1[r];
    mb[2048 + lane] = l_run;
  }
  __syncthreads();
  if (half == 0) {
    float* mb = mbuf + wave * MS;
#pragma unroll
    for (int r = 0; r < 16; ++r) oacc0[r] += mb[r * 64 + lane];
#pragma unroll
    for (int r = 0; r < 16; ++r) oacc1[r] += mb[1024 + r * 64 + lane];
    l_run += mb[2048 + lane];

    // ---- epilogue: normalize (l via shfl) and store ----
    const int n = nh >> 3, h = nh & 7;
    const size_t obase = (size_t)(n * COUT + h * DH) * T_SEQ;
    const int d0 = ln, d1 = 32 + ln;
#pragma unroll
    for (int rq = 0; rq < 4; ++rq) {
      const int tbase = tq0 + 8 * rq + 4 * hi;
      f32x4 o0, o1;
#pragma unroll
      for (int j = 0; j < 4; ++j) {
        const float lv = __shfl(l_run, 8 * rq + 4 * hi + j);
        const float inv = __builtin_amdgcn_rcpf(lv);
        o0[j] = oacc0[4 * rq + j] * inv;
        o1[j] = oacc1[4 * rq + j] * inv;
      }
      *(f32x4*)&outp[obase + (size_t)d0 * T_SEQ + tbase] = o0;
      *(f32x4*)&outp[obase + (size_t)d1 * T_SEQ + tbase] = o1;
    }
  }
}

extern "C" void kernel_launch(void* const* d_in, const int* in_sizes, int n_in,
                              void* d_out, int out_size, void* d_ws, size_t ws_size,
                              hipStream_t stream) {
  (void)in_sizes; (void)n_in; (void)out_size; (void)ws_size;
  const float* x  = (const float*)d_in[0];
  const float* Wq = (const float*)d_in[1];
  const float* Wk = (const float*)d_in[2];
  const float* Wv = (const float*)d_in[3];
  float* outp = (float*)d_out;

  char* ws = (char*)d_ws;
  unsigned short* wb = (unsigned short*)ws;                       // 786432 B
  unsigned short* xT = (unsigned short*)(ws + 786432);            // 4194304 B
  unsigned short* qb = (unsigned short*)(ws + 4980736);           // 8388608 B each
  unsigned short* kb = qb + 4194304;
  unsigned short* vb = kb + 4194304;                              // vb is d-major [nh][64][2048]

  pack_w_k<<<1536, 256, 0, stream>>>(Wq, Wk, Wv, wb);
  pack_xT_k<<<dim3(32, 4, 4), 256, 0, stream>>>(x, xT);
  proj_k<<<dim3(8, 16, 12), 256, 0, stream>>>(wb, xT, qb, kb, vb);
  attn_k<<<512, 512, 0, stream>>>(qb, kb, vb, outp);
}